// Round 4
// baseline (4910.098 us; speedup 1.0000x reference)
//
#include <hip/hip_runtime.h>

#define C 128
#define NPOS 16384      // 128*128 elements per (b,line) slab
#define PLANE 2097152   // 128*128*128 elements per batch

// ---------------------------------------------------------------------------
// Layouts (all fp32):
//   x,y,out : [B][C][H][W]
//   xt      : [B][W][H][C]  phase-1 scan input  (slab rows = H, 512B each)
//   yt1     : [B][W][H][C]  phase-1 gate
//   yt2     : [B][H][W][C]  phase-2 gate        (slab rows = W)
//   hs_t/hn_t: [B][H][W][C] phase-1 out == phase-2 in
//   outA=xt, outB=yt1 : [B][H][W][C] accumulators after phase 1 frees them
// ---------------------------------------------------------------------------

__global__ __launch_bounds__(256) void k_transpose_x(const float* __restrict__ x,
                                                     float* __restrict__ xt) {
  __shared__ float tile[128][129];
  const int b = blockIdx.x >> 7;
  const int h = blockIdx.x & 127;
  const int t = threadIdx.x;
  const int half = t >> 7;
  const int lane = t & 127;
  const float* src = x + (size_t)b * PLANE + (size_t)h * 128;  // [c][w]
  for (int c0 = 0; c0 < 128; c0 += 2) {
    const int c = c0 + half;
    tile[c][lane] = src[(size_t)c * NPOS + lane];
  }
  __syncthreads();
  float* dst = xt + (size_t)b * PLANE + (size_t)h * 128;  // [w][c]
  for (int w0 = 0; w0 < 128; w0 += 2) {
    const int w = w0 + half;
    dst[(size_t)w * NPOS + lane] = tile[lane][w];
  }
}

__global__ __launch_bounds__(256) void k_transpose_y(const float* __restrict__ y,
                                                     float* __restrict__ yt1,
                                                     float* __restrict__ yt2) {
  __shared__ float tile[128][129];
  const int b = blockIdx.x >> 7;
  const int h = blockIdx.x & 127;
  const int t = threadIdx.x;
  const int half = t >> 7;
  const int lane = t & 127;
  const float* src = y + (size_t)b * PLANE + (size_t)h * 128;
  for (int c0 = 0; c0 < 128; c0 += 2) {
    const int c = c0 + half;
    tile[c][lane] = src[(size_t)c * NPOS + lane];
  }
  __syncthreads();
  float* d1 = yt1 + (size_t)b * PLANE + (size_t)h * 128;   // [w][c]
  float* d2 = yt2 + ((size_t)(b * 128 + h)) * NPOS;        // [w][c] row-contig
  for (int w0 = 0; w0 < 128; w0 += 2) {
    const int w = w0 + half;
    const float v = tile[lane][w];
    d1[(size_t)w * NPOS + lane] = v;
    d2[(size_t)w * 128 + lane] = v;
  }
}

__device__ __forceinline__ float4 f4fma(float4 a, float4 b, float4 acc) {
  acc.x = fmaf(a.x, b.x, acc.x);
  acc.y = fmaf(a.y, b.y, acc.y);
  acc.z = fmaf(a.z, b.z, acc.z);
  acc.w = fmaf(a.w, b.w, acc.w);
  return acc;
}

// async global->LDS: 64 lanes x 16B = 1KB (one row pair), linear LDS dest.
__device__ __forceinline__ void ld_pair(const float* g, float* l) {
  __builtin_amdgcn_global_load_lds(
      (const __attribute__((address_space(1))) void*)g,
      (__attribute__((address_space(3))) void*)l, 16, 0, 0);
}

// ---------------------------------------------------------------------------
// One directional gated scan for a single line, FF conv folded one step ahead.
// 256 threads = 4 waves. Lane (wv, q=l>>4, cs=l&15): out channels ch=wv*32+2cs,
// input-channel quarter [q*32, q*32+32). Wa,Wb fragments resident (128 VGPR).
// Global streams (in, gate, old) flow through 8-slot LDS rings filled by
// global_load_lds issued 6-7 rows ahead; counted vmcnt keeps loads in flight
// across raw s_barrier (no compiler vmcnt(0) drain). One barrier per step.
//
// Ring schedule (per wave, FIFO vmcnt arithmetic):
//   prologue: pairs covering P(0..7), then vmcnt(0).
//   even step s (s<=120): issue pair covering {P(s+6),P(s+7)}.
//   binding use: FF dot at step s+1 reads row P(s+2), issued at even step
//   s-4 (s even) / s-5 (s odd). Ops issued after that pair within the
//   region-ordered stream: <=9 (non-ACCUM) / <=11 (ACCUM), so end-of-step
//   waits vmcnt(8) / vmcnt(10) guarantee completion with margin 1.
// ---------------------------------------------------------------------------
template <bool RELU_FIRST, bool REVERSE, bool ACCUM>
__device__ __forceinline__ void scan_line(
    const float* __restrict__ in_slab, const float* __restrict__ gate_slab,
    float* __restrict__ out_base, int out_stride,
    const float* __restrict__ Wa, const float* __restrict__ Ba,
    const float* __restrict__ Wb, const float* __restrict__ Bb,
    float* __restrict__ hbuf, float* __restrict__ in_ring,
    float* __restrict__ gt_ring, float* __restrict__ old_ring) {
  const int t = threadIdx.x;
  const int wv = t >> 6, l = t & 63, q = l >> 4, cs = l & 15;
  const int ch = wv * 32 + cs * 2;
  const bool leader = (q == 0);
  const int lane4 = l * 4;  // float offset of this lane's 16B in a row pair
  const int q2 = 2 * q;

  // rotated word offsets: quarter q reads ring words in order (i+2q)&7 so the
  // four quarters of a wave hit disjoint bank groups per ds_read_b128.
  int roff[8];
#pragma unroll
  for (int i = 0; i < 8; ++i) roff[i] = q * 32 + ((i + q2) & 7) * 4;

  float4 wa_[2][8], wb_[2][8];
#pragma unroll
  for (int i = 0; i < 8; ++i) {
    const int wrot = (i + q2) & 7;
    wa_[0][i] = *(const float4*)(Wa + (size_t)ch * C + q * 32 + wrot * 4);
    wa_[1][i] = *(const float4*)(Wa + (size_t)(ch + 1) * C + q * 32 + wrot * 4);
    wb_[0][i] = *(const float4*)(Wb + (size_t)ch * C + q * 32 + i * 4);
    wb_[1][i] = *(const float4*)(Wb + (size_t)(ch + 1) * C + q * 32 + i * 4);
  }
  float ba0 = 0.f, ba1 = 0.f, bb0 = 0.f, bb1 = 0.f;
  if (leader) {
    ba0 = Ba[ch];
    ba1 = Ba[ch + 1];
    bb0 = Bb[ch];
    bb1 = Bb[ch + 1];
  }

  auto P = [](int s) -> int { return REVERSE ? (127 - s) : s; };
  auto RO = [](int r) -> int { return ((r >> 1) & 7) * 256 + (r & 1) * 128; };

  // prologue: prefetch row pairs covering P(0..7) for every stream
#pragma unroll
  for (int k2 = 0; k2 < 4; ++k2) {
    const int r = P(2 * k2) & ~1;
    const int slot = ((r >> 1) & 7) * 256;
    ld_pair(in_slab + (size_t)r * C + lane4, in_ring + slot);
    ld_pair(gate_slab + (size_t)r * C + lane4, gt_ring + slot);
    if (ACCUM) ld_pair(out_base + (size_t)r * C + lane4, old_ring + slot);
  }
  asm volatile("s_waitcnt vmcnt(0)" ::: "memory");

  // step 0: h0 = (relu?)(in[P(0)])
  if (leader) {
    const float* r0 = in_ring + RO(P(0));
    float hx = r0[ch], hy = r0[ch + 1];
    if (RELU_FIRST) {
      hx = fmaxf(hx, 0.f);
      hy = fmaxf(hy, 0.f);
    }
    float ox = hx, oy = hy;
    if (ACCUM) {
      const float* o0 = old_ring + RO(P(0));
      ox += o0[ch];
      oy += o0[ch + 1];
    }
    hbuf[wv * 36 + cs * 2] = hx;
    hbuf[wv * 36 + cs * 2 + 1] = hy;
    *(float2*)(out_base + (size_t)P(0) * out_stride + ch) = make_float2(ox, oy);
  }

  // ra for step 1 (FF dot on in[P(1)])
  float ra0, ra1;
  {
    const float* rr = in_ring + RO(P(1));
    float4 c0 = {0, 0, 0, 0}, c1 = {0, 0, 0, 0};
#pragma unroll
    for (int i = 0; i < 8; ++i) {
      const float4 v = *(const float4*)(rr + roff[i]);
      c0 = f4fma(wa_[0][i], v, c0);
      c1 = f4fma(wa_[1][i], v, c1);
    }
    ra0 = (c0.x + c0.y) + (c0.z + c0.w);
    ra1 = (c1.x + c1.y) + (c1.z + c1.w);
    ra0 += __shfl_xor(ra0, 16);
    ra0 += __shfl_xor(ra0, 32);
    ra1 += __shfl_xor(ra1, 16);
    ra1 += __shfl_xor(ra1, 32);
  }
  // fence + barrier in one asm: compiler cannot move memory ops across it.
  asm volatile("s_waitcnt lgkmcnt(0)\n\ts_barrier" ::: "memory");

#pragma unroll 1
  for (int s = 1; s < 128; ++s) {
    // issue ring prefetch for the pair covering {P(s+6), P(s+7)}
    if (!(s & 1) && s <= 120) {
      const int r = P(s + 6) & ~1;
      const int slot = ((r >> 1) & 7) * 256;
      ld_pair(in_slab + (size_t)r * C + lane4, in_ring + slot);
      ld_pair(gate_slab + (size_t)r * C + lane4, gt_ring + slot);
      if (ACCUM) ld_pair(out_base + (size_t)r * C + lane4, old_ring + slot);
    }

    // recurrent dot on h_{s-1} (padded LDS, conflict-free)
    const float* hq = hbuf + ((s - 1) & 1) * 144 + q * 36;
    float4 b0 = {0, 0, 0, 0}, b1 = {0, 0, 0, 0};
#pragma unroll
    for (int i = 0; i < 8; ++i) {
      const float4 hv = *(const float4*)(hq + i * 4);
      b0 = f4fma(wb_[0][i], hv, b0);
      b1 = f4fma(wb_[1][i], hv, b1);
    }
    float rb0 = (b0.x + b0.y) + (b0.z + b0.w);
    float rb1 = (b1.x + b1.y) + (b1.z + b1.w);

    // FF dot for step s+1 from the ring
    float rn0 = 0.f, rn1 = 0.f;
    if (s < 127) {
      const float* rr = in_ring + RO(P(s + 1));
      float4 c0 = {0, 0, 0, 0}, c1 = {0, 0, 0, 0};
#pragma unroll
      for (int i = 0; i < 8; ++i) {
        const float4 v = *(const float4*)(rr + roff[i]);
        c0 = f4fma(wa_[0][i], v, c0);
        c1 = f4fma(wa_[1][i], v, c1);
      }
      rn0 = (c0.x + c0.y) + (c0.z + c0.w);
      rn1 = (c1.x + c1.y) + (c1.z + c1.w);
    }

    rb0 += __shfl_xor(rb0, 16);
    rb0 += __shfl_xor(rb0, 32);
    rb1 += __shfl_xor(rb1, 16);
    rb1 += __shfl_xor(rb1, 32);
    rn0 += __shfl_xor(rn0, 16);
    rn0 += __shfl_xor(rn0, 32);
    rn1 += __shfl_xor(rn1, 16);
    rn1 += __shfl_xor(rn1, 32);

    if (leader) {
      const float* gr = gt_ring + RO(P(s - 1));  // gate y_{s-1} for step s
      const float gx = gr[ch], gy = gr[ch + 1];
      float hx = fmaxf(ra0 + ba0 + (rb0 + bb0) * gx, 0.f);
      float hy = fmaxf(ra1 + ba1 + (rb1 + bb1) * gy, 0.f);
      hbuf[(s & 1) * 144 + wv * 36 + cs * 2] = hx;
      hbuf[(s & 1) * 144 + wv * 36 + cs * 2 + 1] = hy;
      float ox = hx, oy = hy;
      if (ACCUM) {
        const float* orow = old_ring + RO(P(s));
        ox += orow[ch];
        oy += orow[ch + 1];
      }
      *(float2*)(out_base + (size_t)P(s) * out_stride + ch) = make_float2(ox, oy);
    }
    ra0 = rn0;
    ra1 = rn1;
    asm volatile("s_waitcnt lgkmcnt(0)\n\ts_barrier" ::: "memory");
    // counted vmcnt: ring pair needed next step forced complete; newer loads
    // and stores stay in flight (never drain to 0 in the loop).
    if (ACCUM)
      asm volatile("s_waitcnt vmcnt(10)" ::: "memory");
    else
      asm volatile("s_waitcnt vmcnt(8)" ::: "memory");
  }
}

// Phase 1: south + north over H. 1024 blocks: [scan(2)][b(4)][w(128)]
__global__ __launch_bounds__(256, 3) void k_scan_ph1(
    const float* __restrict__ xt, const float* __restrict__ yt1,
    float* __restrict__ hs_t, float* __restrict__ hn_t,
    const float* w1, const float* b1, const float* w2, const float* b2,
    const float* w9, const float* b9, const float* w10, const float* b10) {
  __shared__ __align__(16) float hbuf[288];
  __shared__ __align__(16) float in_ring[2048];
  __shared__ __align__(16) float gt_ring[2048];
  const int id = blockIdx.x;
  const int scan = id >> 9;
  const int col = id & 511;  // b*128 + w
  const int b = col >> 7, wc = col & 127;
  const float* in = xt + (size_t)col * NPOS;
  const float* gt = yt1 + (size_t)col * NPOS;
  if (scan == 0)
    scan_line<false, false, false>(in, gt, hs_t + (size_t)b * PLANE + (size_t)wc * C, NPOS,
                                   w1, b1, w2, b2, hbuf, in_ring, gt_ring, nullptr);
  else
    scan_line<true, true, false>(in, gt, hn_t + (size_t)b * PLANE + (size_t)wc * C, NPOS,
                                 w9, b9, w10, b10, hbuf, in_ring, gt_ring, nullptr);
}

// Phase 2a: SE (hs->outA) and NE (hn->outB), forward, store.
__global__ __launch_bounds__(256, 3) void k_scan_ph2a(
    const float* __restrict__ hs_t, const float* __restrict__ hn_t,
    const float* __restrict__ yt2, float* __restrict__ outA, float* __restrict__ outB,
    const float* w4, const float* b4, const float* w5, const float* b5,
    const float* w12, const float* b12, const float* w13, const float* b13) {
  __shared__ __align__(16) float hbuf[288];
  __shared__ __align__(16) float in_ring[2048];
  __shared__ __align__(16) float gt_ring[2048];
  const int id = blockIdx.x;
  const int grp = id >> 9;
  const int col = id & 511;  // b*128 + h
  const size_t base = (size_t)col * NPOS;
  const float* gt = yt2 + base;
  if (grp == 0)
    scan_line<true, false, false>(hs_t + base, gt, outA + base, C, w4, b4, w5, b5,
                                  hbuf, in_ring, gt_ring, nullptr);
  else
    scan_line<true, false, false>(hn_t + base, gt, outB + base, C, w12, b12, w13, b13,
                                  hbuf, in_ring, gt_ring, nullptr);
}

// Phase 2b: SW (hs, RMW into outA) and NW (hn, RMW into outB), reverse.
__global__ __launch_bounds__(256, 3) void k_scan_ph2b(
    const float* __restrict__ hs_t, const float* __restrict__ hn_t,
    const float* __restrict__ yt2, float* __restrict__ outA, float* __restrict__ outB,
    const float* w7, const float* b7, const float* w8, const float* b8,
    const float* w15, const float* b15, const float* w16, const float* b16) {
  __shared__ __align__(16) float hbuf[288];
  __shared__ __align__(16) float in_ring[2048];
  __shared__ __align__(16) float gt_ring[2048];
  __shared__ __align__(16) float old_ring[2048];
  const int id = blockIdx.x;
  const int grp = id >> 9;
  const int col = id & 511;  // b*128 + h
  const size_t base = (size_t)col * NPOS;
  const float* gt = yt2 + base;
  if (grp == 0)
    scan_line<true, true, true>(hs_t + base, gt, outA + base, C, w7, b7, w8, b8,
                                hbuf, in_ring, gt_ring, old_ring);
  else
    scan_line<true, true, true>(hn_t + base, gt, outB + base, C, w15, b15, w16, b16,
                                hbuf, in_ring, gt_ring, old_ring);
}

// out[b][c][h][w] = outA[b][h][w][c] + outB[b][h][w][c]
__global__ __launch_bounds__(256) void k_final(const float* __restrict__ outA,
                                               const float* __restrict__ outB,
                                               float* __restrict__ out) {
  __shared__ float tile[128][129];
  const int b = blockIdx.x >> 7;
  const int h = blockIdx.x & 127;
  const int t = threadIdx.x;
  const int half = t >> 7;
  const int lane = t & 127;
  const float* pa = outA + ((size_t)(b * 128 + h)) * NPOS;  // [w][c]
  const float* pb = outB + ((size_t)(b * 128 + h)) * NPOS;
  for (int w0 = 0; w0 < 128; w0 += 2) {
    const int w = w0 + half;
    tile[w][lane] = pa[(size_t)w * 128 + lane] + pb[(size_t)w * 128 + lane];
  }
  __syncthreads();
  float* dst = out + (size_t)b * PLANE + (size_t)h * 128;  // [c][w]
  for (int c0 = 0; c0 < 128; c0 += 2) {
    const int c = c0 + half;
    dst[(size_t)c * NPOS + lane] = tile[lane][c];
  }
}

extern "C" void kernel_launch(void* const* d_in, const int* in_sizes, int n_in,
                              void* d_out, int out_size, void* d_ws, size_t ws_size,
                              hipStream_t stream) {
  const float* x = (const float*)d_in[0];
  const float* y = (const float*)d_in[1];
  const float* w1 = (const float*)d_in[2];
  const float* b1 = (const float*)d_in[3];
  const float* w2 = (const float*)d_in[4];
  const float* b2 = (const float*)d_in[5];
  const float* w4 = (const float*)d_in[6];
  const float* b4 = (const float*)d_in[7];
  const float* w5 = (const float*)d_in[8];
  const float* b5 = (const float*)d_in[9];
  const float* w7 = (const float*)d_in[10];
  const float* b7 = (const float*)d_in[11];
  const float* w8 = (const float*)d_in[12];
  const float* b8 = (const float*)d_in[13];
  const float* w9 = (const float*)d_in[14];
  const float* b9 = (const float*)d_in[15];
  const float* w10 = (const float*)d_in[16];
  const float* b10 = (const float*)d_in[17];
  const float* w12 = (const float*)d_in[18];
  const float* b12 = (const float*)d_in[19];
  const float* w13 = (const float*)d_in[20];
  const float* b13 = (const float*)d_in[21];
  const float* w15 = (const float*)d_in[22];
  const float* b15 = (const float*)d_in[23];
  const float* w16 = (const float*)d_in[24];
  const float* b16 = (const float*)d_in[25];

  const size_t N1 = (size_t)4 * C * 128 * 128;  // 8M floats = 32MB
  if (ws_size < 5 * N1 * sizeof(float)) return;

  float* ws = (float*)d_ws;
  float* xt = ws;
  float* yt1 = ws + N1;
  float* yt2 = ws + 2 * N1;
  float* hs_t = ws + 3 * N1;
  float* hn_t = ws + 4 * N1;
  float* outA = xt;   // free after phase 1
  float* outB = yt1;  // free after phase 1

  dim3 blk(256);
  k_transpose_x<<<512, blk, 0, stream>>>(x, xt);
  k_transpose_y<<<512, blk, 0, stream>>>(y, yt1, yt2);
  k_scan_ph1<<<1024, blk, 0, stream>>>(xt, yt1, hs_t, hn_t, w1, b1, w2, b2, w9, b9, w10, b10);
  k_scan_ph2a<<<1024, blk, 0, stream>>>(hs_t, hn_t, yt2, outA, outB,
                                        w4, b4, w5, b5, w12, b12, w13, b13);
  k_scan_ph2b<<<1024, blk, 0, stream>>>(hs_t, hn_t, yt2, outA, outB,
                                        w7, b7, w8, b8, w15, b15, w16, b16);
  k_final<<<512, blk, 0, stream>>>(outA, outB, (float*)d_out);
}

// Round 5
// 778.188 us; speedup vs baseline: 6.3097x; 6.3097x over previous
//
#include <hip/hip_runtime.h>

#define C 128
#define NPOS 16384      // 128*128 elements per (b,line) slab
#define PLANE 2097152   // 128*128*128 elements per batch

// ---------------------------------------------------------------------------
// Layouts (all fp32):
//   x,y,out : [B][C][H][W]
//   xt      : [B][W][H][C]  phase-1 scan input  (slab rows = H, 512B each)
//   yt1     : [B][W][H][C]  phase-1 gate
//   yt2     : [B][H][W][C]  phase-2 gate        (slab rows = W)
//   hs_t/hn_t: [B][H][W][C] phase-1 out == phase-2 in
//   outA=xt, outB=yt1 : [B][H][W][C] accumulators after phase 1 frees them
// ---------------------------------------------------------------------------

__global__ __launch_bounds__(256) void k_transpose_x(const float* __restrict__ x,
                                                     float* __restrict__ xt) {
  __shared__ float tile[128][129];
  const int b = blockIdx.x >> 7;
  const int h = blockIdx.x & 127;
  const int t = threadIdx.x;
  const int half = t >> 7;
  const int lane = t & 127;
  const float* src = x + (size_t)b * PLANE + (size_t)h * 128;  // [c][w]
  for (int c0 = 0; c0 < 128; c0 += 2) {
    const int c = c0 + half;
    tile[c][lane] = src[(size_t)c * NPOS + lane];
  }
  __syncthreads();
  float* dst = xt + (size_t)b * PLANE + (size_t)h * 128;  // [w][c]
  for (int w0 = 0; w0 < 128; w0 += 2) {
    const int w = w0 + half;
    dst[(size_t)w * NPOS + lane] = tile[lane][w];
  }
}

__global__ __launch_bounds__(256) void k_transpose_y(const float* __restrict__ y,
                                                     float* __restrict__ yt1,
                                                     float* __restrict__ yt2) {
  __shared__ float tile[128][129];
  const int b = blockIdx.x >> 7;
  const int h = blockIdx.x & 127;
  const int t = threadIdx.x;
  const int half = t >> 7;
  const int lane = t & 127;
  const float* src = y + (size_t)b * PLANE + (size_t)h * 128;
  for (int c0 = 0; c0 < 128; c0 += 2) {
    const int c = c0 + half;
    tile[c][lane] = src[(size_t)c * NPOS + lane];
  }
  __syncthreads();
  float* d1 = yt1 + (size_t)b * PLANE + (size_t)h * 128;   // [w][c]
  float* d2 = yt2 + ((size_t)(b * 128 + h)) * NPOS;        // [w][c] row-contig
  for (int w0 = 0; w0 < 128; w0 += 2) {
    const int w = w0 + half;
    const float v = tile[lane][w];
    d1[(size_t)w * NPOS + lane] = v;
    d2[(size_t)w * 128 + lane] = v;
  }
}

__device__ __forceinline__ float4 f4fma(float4 a, float4 b, float4 acc) {
  acc.x = fmaf(a.x, b.x, acc.x);
  acc.y = fmaf(a.y, b.y, acc.y);
  acc.z = fmaf(a.z, b.z, acc.z);
  acc.w = fmaf(a.w, b.w, acc.w);
  return acc;
}

// async global->LDS: 64 lanes x 16B = 1KB (one row pair), linear LDS dest.
__device__ __forceinline__ void ld_pair(const float* g, float* l) {
  __builtin_amdgcn_global_load_lds(
      (const __attribute__((address_space(1))) void*)g,
      (__attribute__((address_space(3))) void*)l, 16, 0, 0);
}

// ---------------------------------------------------------------------------
// One directional gated scan for a single line, FF conv folded one step ahead.
// 256 threads = 4 waves. Lane (wv, q=l>>4, cs=l&15): out channels ch=wv*32+2cs,
// input-channel quarter [q*32, q*32+32). Wa,Wb fragments resident (128 VGPR —
// requires the launch_bounds(256,2) VGPR cap of 256; (256,3)'s 168 cap spills
// them to scratch: round-4 showed VGPR=84, 2.5GB fetch, 7% VALU).
// Global streams (in, gate, old) flow through 8-slot LDS rings filled by
// global_load_lds issued 6-7 rows ahead; counted vmcnt keeps loads in flight
// across raw s_barrier (no compiler vmcnt(0) drain). One barrier per step.
//
// Ring schedule (per wave, FIFO vmcnt arithmetic):
//   prologue: pairs covering P(0..7), then vmcnt(0).
//   even step s (s<=120): issue pair covering {P(s+6),P(s+7)}.
//   binding use: FF dot at step s+1 reads row P(s+2), issued at even step
//   s-4 (s even) / s-5 (s odd). Ops issued after that pair within the
//   region-ordered stream: <=9 (non-ACCUM) / <=11 (ACCUM), so end-of-step
//   waits vmcnt(8) / vmcnt(10) guarantee completion with margin 1.
// ---------------------------------------------------------------------------
template <bool RELU_FIRST, bool REVERSE, bool ACCUM>
__device__ __forceinline__ void scan_line(
    const float* __restrict__ in_slab, const float* __restrict__ gate_slab,
    float* __restrict__ out_base, int out_stride,
    const float* __restrict__ Wa, const float* __restrict__ Ba,
    const float* __restrict__ Wb, const float* __restrict__ Bb,
    float* __restrict__ hbuf, float* __restrict__ in_ring,
    float* __restrict__ gt_ring, float* __restrict__ old_ring) {
  const int t = threadIdx.x;
  const int wv = t >> 6, l = t & 63, q = l >> 4, cs = l & 15;
  const int ch = wv * 32 + cs * 2;
  const bool leader = (q == 0);
  const int lane4 = l * 4;  // float offset of this lane's 16B in a row pair
  const int q2 = 2 * q;

  // rotated word offsets: quarter q reads ring words in order (i+2q)&7 so the
  // four quarters of a wave hit disjoint bank groups per ds_read_b128.
  int roff[8];
#pragma unroll
  for (int i = 0; i < 8; ++i) roff[i] = q * 32 + ((i + q2) & 7) * 4;

  float4 wa_[2][8], wb_[2][8];
#pragma unroll
  for (int i = 0; i < 8; ++i) {
    const int wrot = (i + q2) & 7;
    wa_[0][i] = *(const float4*)(Wa + (size_t)ch * C + q * 32 + wrot * 4);
    wa_[1][i] = *(const float4*)(Wa + (size_t)(ch + 1) * C + q * 32 + wrot * 4);
    wb_[0][i] = *(const float4*)(Wb + (size_t)ch * C + q * 32 + i * 4);
    wb_[1][i] = *(const float4*)(Wb + (size_t)(ch + 1) * C + q * 32 + i * 4);
  }
  float ba0 = 0.f, ba1 = 0.f, bb0 = 0.f, bb1 = 0.f;
  if (leader) {
    ba0 = Ba[ch];
    ba1 = Ba[ch + 1];
    bb0 = Bb[ch];
    bb1 = Bb[ch + 1];
  }

  auto P = [](int s) -> int { return REVERSE ? (127 - s) : s; };
  auto RO = [](int r) -> int { return ((r >> 1) & 7) * 256 + (r & 1) * 128; };

  // prologue: prefetch row pairs covering P(0..7) for every stream
#pragma unroll
  for (int k2 = 0; k2 < 4; ++k2) {
    const int r = P(2 * k2) & ~1;
    const int slot = ((r >> 1) & 7) * 256;
    ld_pair(in_slab + (size_t)r * C + lane4, in_ring + slot);
    ld_pair(gate_slab + (size_t)r * C + lane4, gt_ring + slot);
    if (ACCUM) ld_pair(out_base + (size_t)r * C + lane4, old_ring + slot);
  }
  asm volatile("s_waitcnt vmcnt(0)" ::: "memory");

  // step 0: h0 = (relu?)(in[P(0)])
  if (leader) {
    const float* r0 = in_ring + RO(P(0));
    float hx = r0[ch], hy = r0[ch + 1];
    if (RELU_FIRST) {
      hx = fmaxf(hx, 0.f);
      hy = fmaxf(hy, 0.f);
    }
    float ox = hx, oy = hy;
    if (ACCUM) {
      const float* o0 = old_ring + RO(P(0));
      ox += o0[ch];
      oy += o0[ch + 1];
    }
    hbuf[wv * 36 + cs * 2] = hx;
    hbuf[wv * 36 + cs * 2 + 1] = hy;
    *(float2*)(out_base + (size_t)P(0) * out_stride + ch) = make_float2(ox, oy);
  }

  // ra for step 1 (FF dot on in[P(1)])
  float ra0, ra1;
  {
    const float* rr = in_ring + RO(P(1));
    float4 c0 = {0, 0, 0, 0}, c1 = {0, 0, 0, 0};
#pragma unroll
    for (int i = 0; i < 8; ++i) {
      const float4 v = *(const float4*)(rr + roff[i]);
      c0 = f4fma(wa_[0][i], v, c0);
      c1 = f4fma(wa_[1][i], v, c1);
    }
    ra0 = (c0.x + c0.y) + (c0.z + c0.w);
    ra1 = (c1.x + c1.y) + (c1.z + c1.w);
    ra0 += __shfl_xor(ra0, 16);
    ra0 += __shfl_xor(ra0, 32);
    ra1 += __shfl_xor(ra1, 16);
    ra1 += __shfl_xor(ra1, 32);
  }
  // fence + barrier in one asm: compiler cannot move memory ops across it.
  asm volatile("s_waitcnt lgkmcnt(0)\n\ts_barrier" ::: "memory");

#pragma unroll 1
  for (int s = 1; s < 128; ++s) {
    // issue ring prefetch for the pair covering {P(s+6), P(s+7)}
    if (!(s & 1) && s <= 120) {
      const int r = P(s + 6) & ~1;
      const int slot = ((r >> 1) & 7) * 256;
      ld_pair(in_slab + (size_t)r * C + lane4, in_ring + slot);
      ld_pair(gate_slab + (size_t)r * C + lane4, gt_ring + slot);
      if (ACCUM) ld_pair(out_base + (size_t)r * C + lane4, old_ring + slot);
    }

    // recurrent dot on h_{s-1} (padded LDS, conflict-free)
    const float* hq = hbuf + ((s - 1) & 1) * 144 + q * 36;
    float4 b0 = {0, 0, 0, 0}, b1 = {0, 0, 0, 0};
#pragma unroll
    for (int i = 0; i < 8; ++i) {
      const float4 hv = *(const float4*)(hq + i * 4);
      b0 = f4fma(wb_[0][i], hv, b0);
      b1 = f4fma(wb_[1][i], hv, b1);
    }
    float rb0 = (b0.x + b0.y) + (b0.z + b0.w);
    float rb1 = (b1.x + b1.y) + (b1.z + b1.w);

    // FF dot for step s+1 from the ring
    float rn0 = 0.f, rn1 = 0.f;
    if (s < 127) {
      const float* rr = in_ring + RO(P(s + 1));
      float4 c0 = {0, 0, 0, 0}, c1 = {0, 0, 0, 0};
#pragma unroll
      for (int i = 0; i < 8; ++i) {
        const float4 v = *(const float4*)(rr + roff[i]);
        c0 = f4fma(wa_[0][i], v, c0);
        c1 = f4fma(wa_[1][i], v, c1);
      }
      rn0 = (c0.x + c0.y) + (c0.z + c0.w);
      rn1 = (c1.x + c1.y) + (c1.z + c1.w);
    }

    rb0 += __shfl_xor(rb0, 16);
    rb0 += __shfl_xor(rb0, 32);
    rb1 += __shfl_xor(rb1, 16);
    rb1 += __shfl_xor(rb1, 32);
    rn0 += __shfl_xor(rn0, 16);
    rn0 += __shfl_xor(rn0, 32);
    rn1 += __shfl_xor(rn1, 16);
    rn1 += __shfl_xor(rn1, 32);

    if (leader) {
      const float* gr = gt_ring + RO(P(s - 1));  // gate y_{s-1} for step s
      const float gx = gr[ch], gy = gr[ch + 1];
      float hx = fmaxf(ra0 + ba0 + (rb0 + bb0) * gx, 0.f);
      float hy = fmaxf(ra1 + ba1 + (rb1 + bb1) * gy, 0.f);
      hbuf[(s & 1) * 144 + wv * 36 + cs * 2] = hx;
      hbuf[(s & 1) * 144 + wv * 36 + cs * 2 + 1] = hy;
      float ox = hx, oy = hy;
      if (ACCUM) {
        const float* orow = old_ring + RO(P(s));
        ox += orow[ch];
        oy += orow[ch + 1];
      }
      *(float2*)(out_base + (size_t)P(s) * out_stride + ch) = make_float2(ox, oy);
    }
    ra0 = rn0;
    ra1 = rn1;
    asm volatile("s_waitcnt lgkmcnt(0)\n\ts_barrier" ::: "memory");
    // counted vmcnt: ring pair needed next step forced complete; newer loads
    // and stores stay in flight (never drain to 0 in the loop).
    if (ACCUM)
      asm volatile("s_waitcnt vmcnt(10)" ::: "memory");
    else
      asm volatile("s_waitcnt vmcnt(8)" ::: "memory");
  }
}

// Phase 1: south + north over H. 1024 blocks: [scan(2)][b(4)][w(128)]
__global__ __launch_bounds__(256, 2) void k_scan_ph1(
    const float* __restrict__ xt, const float* __restrict__ yt1,
    float* __restrict__ hs_t, float* __restrict__ hn_t,
    const float* w1, const float* b1, const float* w2, const float* b2,
    const float* w9, const float* b9, const float* w10, const float* b10) {
  __shared__ __align__(16) float hbuf[288];
  __shared__ __align__(16) float in_ring[2048];
  __shared__ __align__(16) float gt_ring[2048];
  const int id = blockIdx.x;
  const int scan = id >> 9;
  const int col = id & 511;  // b*128 + w
  const int b = col >> 7, wc = col & 127;
  const float* in = xt + (size_t)col * NPOS;
  const float* gt = yt1 + (size_t)col * NPOS;
  if (scan == 0)
    scan_line<false, false, false>(in, gt, hs_t + (size_t)b * PLANE + (size_t)wc * C, NPOS,
                                   w1, b1, w2, b2, hbuf, in_ring, gt_ring, nullptr);
  else
    scan_line<true, true, false>(in, gt, hn_t + (size_t)b * PLANE + (size_t)wc * C, NPOS,
                                 w9, b9, w10, b10, hbuf, in_ring, gt_ring, nullptr);
}

// Phase 2a: SE (hs->outA) and NE (hn->outB), forward, store.
__global__ __launch_bounds__(256, 2) void k_scan_ph2a(
    const float* __restrict__ hs_t, const float* __restrict__ hn_t,
    const float* __restrict__ yt2, float* __restrict__ outA, float* __restrict__ outB,
    const float* w4, const float* b4, const float* w5, const float* b5,
    const float* w12, const float* b12, const float* w13, const float* b13) {
  __shared__ __align__(16) float hbuf[288];
  __shared__ __align__(16) float in_ring[2048];
  __shared__ __align__(16) float gt_ring[2048];
  const int id = blockIdx.x;
  const int grp = id >> 9;
  const int col = id & 511;  // b*128 + h
  const size_t base = (size_t)col * NPOS;
  const float* gt = yt2 + base;
  if (grp == 0)
    scan_line<true, false, false>(hs_t + base, gt, outA + base, C, w4, b4, w5, b5,
                                  hbuf, in_ring, gt_ring, nullptr);
  else
    scan_line<true, false, false>(hn_t + base, gt, outB + base, C, w12, b12, w13, b13,
                                  hbuf, in_ring, gt_ring, nullptr);
}

// Phase 2b: SW (hs, RMW into outA) and NW (hn, RMW into outB), reverse.
__global__ __launch_bounds__(256, 2) void k_scan_ph2b(
    const float* __restrict__ hs_t, const float* __restrict__ hn_t,
    const float* __restrict__ yt2, float* __restrict__ outA, float* __restrict__ outB,
    const float* w7, const float* b7, const float* w8, const float* b8,
    const float* w15, const float* b15, const float* w16, const float* b16) {
  __shared__ __align__(16) float hbuf[288];
  __shared__ __align__(16) float in_ring[2048];
  __shared__ __align__(16) float gt_ring[2048];
  __shared__ __align__(16) float old_ring[2048];
  const int id = blockIdx.x;
  const int grp = id >> 9;
  const int col = id & 511;  // b*128 + h
  const size_t base = (size_t)col * NPOS;
  const float* gt = yt2 + base;
  if (grp == 0)
    scan_line<true, true, true>(hs_t + base, gt, outA + base, C, w7, b7, w8, b8,
                                hbuf, in_ring, gt_ring, old_ring);
  else
    scan_line<true, true, true>(hn_t + base, gt, outB + base, C, w15, b15, w16, b16,
                                hbuf, in_ring, gt_ring, old_ring);
}

// out[b][c][h][w] = outA[b][h][w][c] + outB[b][h][w][c]
__global__ __launch_bounds__(256) void k_final(const float* __restrict__ outA,
                                               const float* __restrict__ outB,
                                               float* __restrict__ out) {
  __shared__ float tile[128][129];
  const int b = blockIdx.x >> 7;
  const int h = blockIdx.x & 127;
  const int t = threadIdx.x;
  const int half = t >> 7;
  const int lane = t & 127;
  const float* pa = outA + ((size_t)(b * 128 + h)) * NPOS;  // [w][c]
  const float* pb = outB + ((size_t)(b * 128 + h)) * NPOS;
  for (int w0 = 0; w0 < 128; w0 += 2) {
    const int w = w0 + half;
    tile[w][lane] = pa[(size_t)w * 128 + lane] + pb[(size_t)w * 128 + lane];
  }
  __syncthreads();
  float* dst = out + (size_t)b * PLANE + (size_t)h * 128;  // [c][w]
  for (int c0 = 0; c0 < 128; c0 += 2) {
    const int c = c0 + half;
    dst[(size_t)c * NPOS + lane] = tile[lane][c];
  }
}

extern "C" void kernel_launch(void* const* d_in, const int* in_sizes, int n_in,
                              void* d_out, int out_size, void* d_ws, size_t ws_size,
                              hipStream_t stream) {
  const float* x = (const float*)d_in[0];
  const float* y = (const float*)d_in[1];
  const float* w1 = (const float*)d_in[2];
  const float* b1 = (const float*)d_in[3];
  const float* w2 = (const float*)d_in[4];
  const float* b2 = (const float*)d_in[5];
  const float* w4 = (const float*)d_in[6];
  const float* b4 = (const float*)d_in[7];
  const float* w5 = (const float*)d_in[8];
  const float* b5 = (const float*)d_in[9];
  const float* w7 = (const float*)d_in[10];
  const float* b7 = (const float*)d_in[11];
  const float* w8 = (const float*)d_in[12];
  const float* b8 = (const float*)d_in[13];
  const float* w9 = (const float*)d_in[14];
  const float* b9 = (const float*)d_in[15];
  const float* w10 = (const float*)d_in[16];
  const float* b10 = (const float*)d_in[17];
  const float* w12 = (const float*)d_in[18];
  const float* b12 = (const float*)d_in[19];
  const float* w13 = (const float*)d_in[20];
  const float* b13 = (const float*)d_in[21];
  const float* w15 = (const float*)d_in[22];
  const float* b15 = (const float*)d_in[23];
  const float* w16 = (const float*)d_in[24];
  const float* b16 = (const float*)d_in[25];

  const size_t N1 = (size_t)4 * C * 128 * 128;  // 8M floats = 32MB
  if (ws_size < 5 * N1 * sizeof(float)) return;

  float* ws = (float*)d_ws;
  float* xt = ws;
  float* yt1 = ws + N1;
  float* yt2 = ws + 2 * N1;
  float* hs_t = ws + 3 * N1;
  float* hn_t = ws + 4 * N1;
  float* outA = xt;   // free after phase 1
  float* outB = yt1;  // free after phase 1

  dim3 blk(256);
  k_transpose_x<<<512, blk, 0, stream>>>(x, xt);
  k_transpose_y<<<512, blk, 0, stream>>>(y, yt1, yt2);
  k_scan_ph1<<<1024, blk, 0, stream>>>(xt, yt1, hs_t, hn_t, w1, b1, w2, b2, w9, b9, w10, b10);
  k_scan_ph2a<<<1024, blk, 0, stream>>>(hs_t, hn_t, yt2, outA, outB,
                                        w4, b4, w5, b5, w12, b12, w13, b13);
  k_scan_ph2b<<<1024, blk, 0, stream>>>(hs_t, hn_t, yt2, outA, outB,
                                        w7, b7, w8, b8, w15, b15, w16, b16);
  k_final<<<512, blk, 0, stream>>>(outA, outB, (float*)d_out);
}

// Round 6
// 430.592 us; speedup vs baseline: 11.4031x; 1.8073x over previous
//
#include <hip/hip_runtime.h>

typedef unsigned int uint;
typedef unsigned short ushort;
typedef __attribute__((ext_vector_type(8))) short short8;  // 8 bf16 = 4 VGPR
typedef __attribute__((ext_vector_type(4))) float f32x4;

#define NPOS 16384
#define PLANE 2097152
// LDS map (bytes): x-ring [4 slots][2 splits] 4KB planes | gate ring [4] 8KB |
// old ring [4] 8KB | H dbuf [2][2 splits] 4KB planes
#define XR_OFF 0
#define GR_OFF 32768
#define OR_OFF 65536
#define HP_OFF 98304
#define LDS_BYTES 114688

__device__ __forceinline__ uint fbits(float a) { return __builtin_bit_cast(uint, a); }
// RNE bf16 high part (unbiased hi split)
__device__ __forceinline__ uint rnehi(float a) {
  const uint u = fbits(a);
  return (u + 0x7FFFu + ((u >> 16) & 1u)) & 0xFFFF0000u;
}
__device__ __forceinline__ float fhi(float a) { return __builtin_bit_cast(float, rnehi(a)); }
__device__ __forceinline__ uint packhi(float a, float b) { return (rnehi(a) >> 16) | rnehi(b); }
__device__ __forceinline__ uint packtr(float a, float b) {
  return (fbits(a) >> 16) | (fbits(b) & 0xFFFF0000u);  // truncating pack (lo parts)
}
__device__ __forceinline__ float b2f(uint h16) { return __builtin_bit_cast(float, h16 << 16); }

__device__ __forceinline__ f32x4 MF(short8 a, short8 b, f32x4 c) {
  return __builtin_amdgcn_mfma_f32_16x16x32_bf16(a, b, c, 0, 0, 0);
}
__device__ __forceinline__ void fill16(const void* g, char* l) {
  __builtin_amdgcn_global_load_lds((const __attribute__((address_space(1))) void*)g,
                                   (__attribute__((address_space(3))) void*)l, 16, 0, 0);
}
// build hi/lo bf16x8 fragments from 8 fp32
__device__ __forceinline__ void split8(float4 v0, float4 v1, short8& hi, short8& lo) {
  union { short8 s; uint u[4]; } H, L;
  H.u[0] = packhi(v0.x, v0.y); H.u[1] = packhi(v0.z, v0.w);
  H.u[2] = packhi(v1.x, v1.y); H.u[3] = packhi(v1.z, v1.w);
  L.u[0] = packtr(v0.x - fhi(v0.x), v0.y - fhi(v0.y));
  L.u[1] = packtr(v0.z - fhi(v0.z), v0.w - fhi(v0.w));
  L.u[2] = packtr(v1.x - fhi(v1.x), v1.y - fhi(v1.y));
  L.u[3] = packtr(v1.z - fhi(v1.z), v1.w - fhi(v1.w));
  hi = H.s; lo = L.s;
}

#define BAR() asm volatile("s_waitcnt lgkmcnt(0)\n\ts_barrier" ::: "memory")

// ---------------------------------------------------------------------------
// x,y,out : [B][C][H][W] fp32
// xt_hi/lo: [B][W][H][C] bf16 split   yt1: [B][W][H][C] fp32   yt2: [B][H][W][C] fp32
// hs/hn_hi/lo: [B][H][W][C] bf16 split (ph1 out = ph2 in)
// outA/outB: [B][H][W][C] fp32 (overlay xt / yt1 after ph1)
// ---------------------------------------------------------------------------

__global__ __launch_bounds__(256) void k_transpose_x(const float* __restrict__ x,
                                                     ushort* __restrict__ xhi,
                                                     ushort* __restrict__ xlo) {
  __shared__ float tile[128][129];
  const int b = blockIdx.x >> 7, h = blockIdx.x & 127;
  const int t = threadIdx.x, half = t >> 7, lane = t & 127;
  const float* src = x + (size_t)b * PLANE + (size_t)h * 128;  // [c][w]
  for (int c0 = 0; c0 < 128; c0 += 2) {
    const int c = c0 + half;
    tile[c][lane] = src[(size_t)c * NPOS + lane];
  }
  __syncthreads();
  const int wq = t >> 6, cp = t & 63;  // ci pair
  for (int w0 = 0; w0 < 128; w0 += 4) {
    const int w = w0 + wq;
    const float v0 = tile[2 * cp][w], v1 = tile[2 * cp + 1][w];
    const size_t e = ((size_t)(b * 128 + w) * 128 + h) * 128 + 2 * cp;
    *(uint*)(xhi + e) = packhi(v0, v1);
    *(uint*)(xlo + e) = packtr(v0 - fhi(v0), v1 - fhi(v1));
  }
}

__global__ __launch_bounds__(256) void k_transpose_y(const float* __restrict__ y,
                                                     float* __restrict__ yt1,
                                                     float* __restrict__ yt2) {
  __shared__ float tile[128][129];
  const int b = blockIdx.x >> 7, h = blockIdx.x & 127;
  const int t = threadIdx.x, half = t >> 7, lane = t & 127;
  const float* src = y + (size_t)b * PLANE + (size_t)h * 128;
  for (int c0 = 0; c0 < 128; c0 += 2) {
    const int c = c0 + half;
    tile[c][lane] = src[(size_t)c * NPOS + lane];
  }
  __syncthreads();
  float* d1 = yt1 + (size_t)b * PLANE + (size_t)h * 128;
  float* d2 = yt2 + ((size_t)(b * 128 + h)) * NPOS;
  for (int w0 = 0; w0 < 128; w0 += 2) {
    const int w = w0 + half;
    const float v = tile[lane][w];
    d1[(size_t)w * NPOS + lane] = v;
    d2[(size_t)w * 128 + lane] = v;
  }
}

// ---------------------------------------------------------------------------
// 16-line batched gated scan, MFMA, bf16 3-term split.
// 4 waves; wave wv owns out rows [32wv,32wv+32) (two 16-row M tiles).
// Lane: line=l&15 (MFMA n / C col), g4=l>>4 (k-group; C rows 4*g4+j).
// H/X LDS planes: [line][128ci] bf16, 16B chunks XOR-swizzled by (line&7).
// gate/old rings: fp32 [line][128], same swizzle. Fills via global_load_lds
// with pre-swizzled global source; counted vmcnt(8) per step (8 = one step's
// per-wave VMEM issue) keeps loads in flight across raw barriers.
// Slots: x/old filled for pos-index s+3 at step s; gate for s+2 (avoids
// overwriting slot (s-1)&3 gate read during step s).
// ---------------------------------------------------------------------------
template <bool RELU0, bool REV, bool ACCUM, bool OUT16>
__device__ __forceinline__ void scan16(
    char* lds,
    const ushort* __restrict__ xhi, const ushort* __restrict__ xlo, size_t in_base,
    const float* __restrict__ gate, size_t gate_base,
    float* __restrict__ outf, ushort* __restrict__ outhi, ushort* __restrict__ outlo,
    size_t out_base, int out_ps, int out_ls,
    const float* __restrict__ Wa, const float* __restrict__ Ba,
    const float* __restrict__ Wb, const float* __restrict__ Bb) {
  const int t = threadIdx.x;
  const int wv = t >> 6, l = t & 63;
  const int line = l & 15, g4 = l >> 4;

  // ---- resident weight fragments: A[m][k], m=l&15 in tile, k=32kt+8*g4+j ----
  short8 wah[2][4], wal[2][4], wbh[2][4], wbl[2][4];
#pragma unroll
  for (int tt = 0; tt < 2; ++tt)
#pragma unroll
    for (int kt = 0; kt < 4; ++kt) {
      const int row = 32 * wv + 16 * tt + line;
      const int kc = 32 * kt + 8 * g4;
      const float4 a0 = *(const float4*)(Wa + row * 128 + kc);
      const float4 a1 = *(const float4*)(Wa + row * 128 + kc + 4);
      const float4 c0 = *(const float4*)(Wb + row * 128 + kc);
      const float4 c1 = *(const float4*)(Wb + row * 128 + kc + 4);
      split8(a0, a1, wah[tt][kt], wal[tt][kt]);
      split8(c0, c1, wbh[tt][kt], wbl[tt][kt]);
    }
  f32x4 baf[2], bbf[2];  // bias fragments (C rows 4*g4+j)
#pragma unroll
  for (int tt = 0; tt < 2; ++tt) {
    baf[tt] = *(const f32x4*)(Ba + 32 * wv + 16 * tt + 4 * g4);
    bbf[tt] = *(const f32x4*)(Bb + 32 * wv + 16 * tt + 4 * g4);
  }

  auto P = [](int p) -> int { return REV ? 127 - p : p; };

  // fill bundles (wave-partitioned; cross-wave visibility via vmcnt+barrier)
  auto fillX = [&](int p, int slot) {
    const ushort* src = (wv >> 1) ? xlo : xhi;
#pragma unroll
    for (int kk = 0; kk < 2; ++kk) {
      const int k = 2 * (wv & 1) + kk;      // instr: 4 lines
      const int lf = 4 * k + g4;            // line
      const int cf = l & 15;                // 16B chunk in line
      const size_t e = in_base + (size_t)lf * NPOS + (size_t)p * 128 + 8 * (cf ^ (lf & 7));
      fill16(src + e, lds + XR_OFF + slot * 8192 + (wv >> 1) * 4096 + k * 1024 + l * 16);
    }
  };
  auto fillG = [&](int p, int slot) {
#pragma unroll
    for (int kk = 0; kk < 2; ++kk) {
      const int k = 2 * wv + kk;            // instr: 2 lines
      const int lf = 2 * k + (l >> 5);
      const int cf = l & 31;
      const size_t e = gate_base + (size_t)lf * NPOS + (size_t)p * 128 + 4 * (cf ^ (lf & 7));
      fill16(gate + e, lds + GR_OFF + slot * 8192 + k * 1024 + l * 16);
    }
  };
  auto fillO = [&](int p, int slot) {
#pragma unroll
    for (int kk = 0; kk < 2; ++kk) {
      const int k = 2 * wv + kk;
      const int lf = 2 * k + (l >> 5);
      const int cf = l & 31;
      const size_t e = out_base + (size_t)p * out_ps + (size_t)lf * out_ls + 4 * (cf ^ (lf & 7));
      fill16(outf + e, lds + OR_OFF + slot * 8192 + k * 1024 + l * 16);
    }
  };

  // ---- prologue: fill slots 0..3 (pos P(0..3)) ----
#pragma unroll
  for (int p = 0; p < 4; ++p) {
    fillX(P(p), p);
    fillG(P(p), p);
    if (ACCUM) fillO(P(p), p);
  }
  asm volatile("s_waitcnt vmcnt(0) lgkmcnt(0)\n\ts_barrier" ::: "memory");

  // ---- step 0: h0 = relu?(x[P(0)]) ----
  {
    const char* X0 = lds + XR_OFF;
    const char* O0 = lds + OR_OFF;
    char* Hwr = lds + HP_OFF;  // dbuf 0
#pragma unroll
    for (int tt = 0; tt < 2; ++tt) {
      const int chw = 4 * wv + 2 * tt + (g4 >> 1);
      const int boff = line * 256 + ((chw ^ (line & 7)) << 4) + 8 * (g4 & 1);
      const uint2 xh = *(const uint2*)(X0 + boff);
      const uint2 xl = *(const uint2*)(X0 + 4096 + boff);
      float4 f;
      f.x = b2f(xh.x & 0xFFFFu) + b2f(xl.x & 0xFFFFu);
      f.y = b2f(xh.x >> 16) + b2f(xl.x >> 16);
      f.z = b2f(xh.y & 0xFFFFu) + b2f(xl.y & 0xFFFFu);
      f.w = b2f(xh.y >> 16) + b2f(xl.y >> 16);
      if (RELU0) {
        f.x = fmaxf(f.x, 0.f); f.y = fmaxf(f.y, 0.f);
        f.z = fmaxf(f.z, 0.f); f.w = fmaxf(f.w, 0.f);
      }
      uint2 hw, lw;
      hw.x = packhi(f.x, f.y); hw.y = packhi(f.z, f.w);
      lw.x = packtr(f.x - fhi(f.x), f.y - fhi(f.y));
      lw.y = packtr(f.z - fhi(f.z), f.w - fhi(f.w));
      *(uint2*)(Hwr + boff) = hw;
      *(uint2*)(Hwr + 4096 + boff) = lw;
      const int ci0 = 32 * wv + 16 * tt + 4 * g4;
      const size_t oe = out_base + (size_t)P(0) * out_ps + (size_t)line * out_ls + ci0;
      if (OUT16) {
        *(uint2*)(outhi + oe) = hw;
        *(uint2*)(outlo + oe) = lw;
      } else {
        float4 o = f;
        if (ACCUM) {
          const int c32 = 8 * wv + 4 * tt + g4;
          const float4 ov = *(const float4*)(O0 + line * 512 + ((c32 ^ (line & 7)) << 4));
          o.x += ov.x; o.y += ov.y; o.z += ov.z; o.w += ov.w;
        }
        *(float4*)(outf + oe) = o;
      }
    }
  }
  BAR();

  // ---- main loop ----
#pragma unroll 1
  for (int s = 1; s < 128; ++s) {
    if (s + 3 <= 127) {
      fillX(P(s + 3), (s + 3) & 3);
      if (ACCUM) fillO(P(s + 3), (s + 3) & 3);
    }
    if (s + 2 <= 127) fillG(P(s + 2), (s + 2) & 3);

    f32x4 accF[2], accR[2];
    accF[0] = baf[0]; accF[1] = baf[1];
    accR[0] = bbf[0]; accR[1] = bbf[1];
    const char* Hrd = lds + HP_OFF + ((s - 1) & 1) * 8192;
    const char* Xrd = lds + XR_OFF + (s & 3) * 8192;
#pragma unroll
    for (int kt = 0; kt < 4; ++kt) {
      const int ro = line * 256 + (((4 * kt + g4) ^ (line & 7)) << 4);
      const short8 hh = *(const short8*)(Hrd + ro);
      const short8 hl = *(const short8*)(Hrd + 4096 + ro);
      const short8 xh = *(const short8*)(Xrd + ro);
      const short8 xl = *(const short8*)(Xrd + 4096 + ro);
      accR[0] = MF(wbh[0][kt], hh, accR[0]);
      accR[0] = MF(wbh[0][kt], hl, accR[0]);
      accR[0] = MF(wbl[0][kt], hh, accR[0]);
      accR[1] = MF(wbh[1][kt], hh, accR[1]);
      accR[1] = MF(wbh[1][kt], hl, accR[1]);
      accR[1] = MF(wbl[1][kt], hh, accR[1]);
      accF[0] = MF(wah[0][kt], xh, accF[0]);
      accF[0] = MF(wah[0][kt], xl, accF[0]);
      accF[0] = MF(wal[0][kt], xh, accF[0]);
      accF[1] = MF(wah[1][kt], xh, accF[1]);
      accF[1] = MF(wah[1][kt], xl, accF[1]);
      accF[1] = MF(wal[1][kt], xh, accF[1]);
    }

    const char* Grd = lds + GR_OFF + ((s - 1) & 3) * 8192;
    const char* Ord = lds + OR_OFF + (s & 3) * 8192;
    char* Hwr = lds + HP_OFF + (s & 1) * 8192;
#pragma unroll
    for (int tt = 0; tt < 2; ++tt) {
      const int c32 = 8 * wv + 4 * tt + g4;
      const float4 g = *(const float4*)(Grd + line * 512 + ((c32 ^ (line & 7)) << 4));
      float4 h;
      h.x = fmaxf(fmaf(accR[tt][0], g.x, accF[tt][0]), 0.f);
      h.y = fmaxf(fmaf(accR[tt][1], g.y, accF[tt][1]), 0.f);
      h.z = fmaxf(fmaf(accR[tt][2], g.z, accF[tt][2]), 0.f);
      h.w = fmaxf(fmaf(accR[tt][3], g.w, accF[tt][3]), 0.f);
      uint2 hw, lw;
      hw.x = packhi(h.x, h.y); hw.y = packhi(h.z, h.w);
      lw.x = packtr(h.x - fhi(h.x), h.y - fhi(h.y));
      lw.y = packtr(h.z - fhi(h.z), h.w - fhi(h.w));
      const int chw = 4 * wv + 2 * tt + (g4 >> 1);
      const int wo = line * 256 + ((chw ^ (line & 7)) << 4) + 8 * (g4 & 1);
      *(uint2*)(Hwr + wo) = hw;
      *(uint2*)(Hwr + 4096 + wo) = lw;
      const int ci0 = 32 * wv + 16 * tt + 4 * g4;
      const size_t oe = out_base + (size_t)P(s) * out_ps + (size_t)line * out_ls + ci0;
      if (OUT16) {
        *(uint2*)(outhi + oe) = hw;
        *(uint2*)(outlo + oe) = lw;
      } else {
        float4 o = h;
        if (ACCUM) {
          const float4 ov = *(const float4*)(Ord + line * 512 + ((c32 ^ (line & 7)) << 4));
          o.x += ov.x; o.y += ov.y; o.z += ov.z; o.w += ov.w;
        }
        *(float4*)(outf + oe) = o;
      }
    }
    BAR();
    asm volatile("s_waitcnt vmcnt(8)" ::: "memory");
  }
}

// Phase 1: 64 blocks = [scan(2)][b(4)][wgrp(8)]; south->hs, north->hn (bf16 split out)
__global__ __launch_bounds__(256, 1) void k_scan_ph1(
    const ushort* __restrict__ xhi, const ushort* __restrict__ xlo,
    const float* __restrict__ yt1,
    ushort* __restrict__ hs_hi, ushort* __restrict__ hs_lo,
    ushort* __restrict__ hn_hi, ushort* __restrict__ hn_lo,
    const float* w1, const float* b1, const float* w2, const float* b2,
    const float* w9, const float* b9, const float* w10, const float* b10) {
  __shared__ __align__(16) char lds[LDS_BYTES];
  const int id = blockIdx.x;
  const int scan = id >> 5, b = (id >> 3) & 3, wg = id & 7;
  const size_t in_base = ((size_t)(b * 128 + wg * 16)) * NPOS;
  const size_t out_base = (size_t)b * PLANE + (size_t)(wg * 16) * 128;
  if (scan == 0)
    scan16<false, false, false, true>(lds, xhi, xlo, in_base, yt1, in_base,
                                      nullptr, hs_hi, hs_lo, out_base, NPOS, 128,
                                      w1, b1, w2, b2);
  else
    scan16<true, true, false, true>(lds, xhi, xlo, in_base, yt1, in_base,
                                    nullptr, hn_hi, hn_lo, out_base, NPOS, 128,
                                    w9, b9, w10, b10);
}

// Phase 2: 64 blocks = [grp(2)][b(4)][hgrp(8)]; grp0: SE then SW(acc) -> outA;
// grp1: NE then NW(acc) -> outB. Pass2 reads pass1's own output via old-ring.
__global__ __launch_bounds__(256, 1) void k_scan_ph2(
    const ushort* __restrict__ hs_hi, const ushort* __restrict__ hs_lo,
    const ushort* __restrict__ hn_hi, const ushort* __restrict__ hn_lo,
    const float* __restrict__ yt2, float* __restrict__ outA, float* __restrict__ outB,
    const float* w4, const float* b4, const float* w5, const float* b5,
    const float* w7, const float* b7, const float* w8, const float* b8,
    const float* w12, const float* b12, const float* w13, const float* b13,
    const float* w15, const float* b15, const float* w16, const float* b16) {
  __shared__ __align__(16) char lds[LDS_BYTES];
  const int id = blockIdx.x;
  const int grp = id >> 5, b = (id >> 3) & 3, hg = id & 7;
  const size_t base = ((size_t)(b * 128 + hg * 16)) * NPOS;
  const ushort* ihi = grp ? hn_hi : hs_hi;
  const ushort* ilo = grp ? hn_lo : hs_lo;
  float* o = grp ? outB : outA;
  const float* wa1 = grp ? w12 : w4; const float* ba1 = grp ? b12 : b4;
  const float* wb1 = grp ? w13 : w5; const float* bb1 = grp ? b13 : b5;
  const float* wa2 = grp ? w15 : w7; const float* ba2 = grp ? b15 : b7;
  const float* wb2 = grp ? w16 : w8; const float* bb2 = grp ? b16 : b8;
  scan16<true, false, false, false>(lds, ihi, ilo, base, yt2, base,
                                    o, nullptr, nullptr, base, 128, NPOS,
                                    wa1, ba1, wb1, bb1);
  asm volatile("s_waitcnt vmcnt(0) lgkmcnt(0)\n\ts_barrier" ::: "memory");
  scan16<true, true, true, false>(lds, ihi, ilo, base, yt2, base,
                                  o, nullptr, nullptr, base, 128, NPOS,
                                  wa2, ba2, wb2, bb2);
}

// out[b][c][h][w] = outA[b][h][w][c] + outB[b][h][w][c]
__global__ __launch_bounds__(256) void k_final(const float* __restrict__ outA,
                                               const float* __restrict__ outB,
                                               float* __restrict__ out) {
  __shared__ float tile[128][129];
  const int b = blockIdx.x >> 7, h = blockIdx.x & 127;
  const int t = threadIdx.x, half = t >> 7, lane = t & 127;
  const float* pa = outA + ((size_t)(b * 128 + h)) * NPOS;
  const float* pb = outB + ((size_t)(b * 128 + h)) * NPOS;
  for (int w0 = 0; w0 < 128; w0 += 2) {
    const int w = w0 + half;
    tile[w][lane] = pa[(size_t)w * 128 + lane] + pb[(size_t)w * 128 + lane];
  }
  __syncthreads();
  float* dst = out + (size_t)b * PLANE + (size_t)h * 128;
  for (int c0 = 0; c0 < 128; c0 += 2) {
    const int c = c0 + half;
    dst[(size_t)c * NPOS + lane] = tile[lane][c];
  }
}

extern "C" void kernel_launch(void* const* d_in, const int* in_sizes, int n_in,
                              void* d_out, int out_size, void* d_ws, size_t ws_size,
                              hipStream_t stream) {
  const float* x = (const float*)d_in[0];
  const float* y = (const float*)d_in[1];
  const float* w1 = (const float*)d_in[2];  const float* b1 = (const float*)d_in[3];
  const float* w2 = (const float*)d_in[4];  const float* b2 = (const float*)d_in[5];
  const float* w4 = (const float*)d_in[6];  const float* b4 = (const float*)d_in[7];
  const float* w5 = (const float*)d_in[8];  const float* b5 = (const float*)d_in[9];
  const float* w7 = (const float*)d_in[10]; const float* b7 = (const float*)d_in[11];
  const float* w8 = (const float*)d_in[12]; const float* b8 = (const float*)d_in[13];
  const float* w9 = (const float*)d_in[14]; const float* b9 = (const float*)d_in[15];
  const float* w10 = (const float*)d_in[16]; const float* b10 = (const float*)d_in[17];
  const float* w12 = (const float*)d_in[18]; const float* b12 = (const float*)d_in[19];
  const float* w13 = (const float*)d_in[20]; const float* b13 = (const float*)d_in[21];
  const float* w15 = (const float*)d_in[22]; const float* b15 = (const float*)d_in[23];
  const float* w16 = (const float*)d_in[24]; const float* b16 = (const float*)d_in[25];

  if (ws_size < 167772160) return;  // 160MB
  char* ws = (char*)d_ws;
  ushort* xt_hi = (ushort*)ws;                         // 0   .. 16MB
  ushort* xt_lo = (ushort*)(ws + 16777216);            // 16  .. 32MB
  float* yt1 = (float*)(ws + 33554432);                // 32  .. 64MB
  float* yt2 = (float*)(ws + 67108864);                // 64  .. 96MB
  ushort* hs_hi = (ushort*)(ws + 100663296);           // 96  .. 112MB
  ushort* hs_lo = (ushort*)(ws + 117440512);           // 112 .. 128MB
  ushort* hn_hi = (ushort*)(ws + 134217728);           // 128 .. 144MB
  ushort* hn_lo = (ushort*)(ws + 150994944);           // 144 .. 160MB
  float* outA = (float*)ws;                            // overlay xt (dead after ph1)
  float* outB = (float*)(ws + 33554432);               // overlay yt1 (dead after ph1)

  dim3 blk(256);
  k_transpose_x<<<512, blk, 0, stream>>>(x, xt_hi, xt_lo);
  k_transpose_y<<<512, blk, 0, stream>>>(y, yt1, yt2);
  k_scan_ph1<<<64, blk, 0, stream>>>(xt_hi, xt_lo, yt1, hs_hi, hs_lo, hn_hi, hn_lo,
                                     w1, b1, w2, b2, w9, b9, w10, b10);
  k_scan_ph2<<<64, blk, 0, stream>>>(hs_hi, hs_lo, hn_hi, hn_lo, yt2, outA, outB,
                                     w4, b4, w5, b5, w7, b7, w8, b8,
                                     w12, b12, w13, b13, w15, b15, w16, b16);
  k_final<<<512, blk, 0, stream>>>(outA, outB, (float*)d_out);
}

// Round 7
// 429.993 us; speedup vs baseline: 11.4190x; 1.0014x over previous
//
#include <hip/hip_runtime.h>

typedef unsigned int uint;
typedef unsigned short ushort;
typedef __attribute__((ext_vector_type(8))) short short8;  // 8 bf16 = 4 VGPR
typedef __attribute__((ext_vector_type(4))) float f32x4;

#define NPOS 16384
#define PLANE 2097152
// LDS map (bytes). All planes fragment-linear: every wave read/write is
// base + lane*16 (or perfect 8B tiling) -> zero bank conflicts.
//   X ring : 4 slots x [hi 4KB | lo 4KB], plane = [chunk c(16)][line(16)] 16B
//   G ring : 4 slots x 8KB fp32, per-wave C-layout slices [wv][tt][l*16]
//   H dbuf : 2 x [hi 4KB | lo 4KB]
//   O ring : 4 slots x 8KB fp32 (ACCUM only; last so ph1 can shrink LDS)
#define XR_OFF 0
#define GR_OFF 32768
#define HP_OFF 65536
#define OR_OFF 81920
#define LDS_PH1 81920
#define LDS_PH2 114688

__device__ __forceinline__ uint fbits(float a) { return __builtin_bit_cast(uint, a); }
__device__ __forceinline__ uint rnehi(float a) {  // RNE bf16 high split
  const uint u = fbits(a);
  return (u + 0x7FFFu + ((u >> 16) & 1u)) & 0xFFFF0000u;
}
__device__ __forceinline__ float fhi(float a) { return __builtin_bit_cast(float, rnehi(a)); }
__device__ __forceinline__ uint packhi(float a, float b) { return (rnehi(a) >> 16) | rnehi(b); }
__device__ __forceinline__ uint packtr(float a, float b) {
  return (fbits(a) >> 16) | (fbits(b) & 0xFFFF0000u);
}
__device__ __forceinline__ float b2f(uint h16) { return __builtin_bit_cast(float, h16 << 16); }

__device__ __forceinline__ f32x4 MF(short8 a, short8 b, f32x4 c) {
  return __builtin_amdgcn_mfma_f32_16x16x32_bf16(a, b, c, 0, 0, 0);
}
__device__ __forceinline__ void fill16(const void* g, char* l) {
  __builtin_amdgcn_global_load_lds((const __attribute__((address_space(1))) void*)g,
                                   (__attribute__((address_space(3))) void*)l, 16, 0, 0);
}
__device__ __forceinline__ void split8(float4 v0, float4 v1, short8& hi, short8& lo) {
  union { short8 s; uint u[4]; } H, L;
  H.u[0] = packhi(v0.x, v0.y); H.u[1] = packhi(v0.z, v0.w);
  H.u[2] = packhi(v1.x, v1.y); H.u[3] = packhi(v1.z, v1.w);
  L.u[0] = packtr(v0.x - fhi(v0.x), v0.y - fhi(v0.y));
  L.u[1] = packtr(v0.z - fhi(v0.z), v0.w - fhi(v0.w));
  L.u[2] = packtr(v1.x - fhi(v1.x), v1.y - fhi(v1.y));
  L.u[3] = packtr(v1.z - fhi(v1.z), v1.w - fhi(v1.w));
  hi = H.s; lo = L.s;
}

#define BAR() asm volatile("s_waitcnt lgkmcnt(0)\n\ts_barrier" ::: "memory")

__global__ __launch_bounds__(256) void k_transpose_x(const float* __restrict__ x,
                                                     ushort* __restrict__ xhi,
                                                     ushort* __restrict__ xlo) {
  __shared__ float tile[128][129];
  const int b = blockIdx.x >> 7, h = blockIdx.x & 127;
  const int t = threadIdx.x, half = t >> 7, lane = t & 127;
  const float* src = x + (size_t)b * PLANE + (size_t)h * 128;  // [c][w]
  for (int c0 = 0; c0 < 128; c0 += 2) {
    const int c = c0 + half;
    tile[c][lane] = src[(size_t)c * NPOS + lane];
  }
  __syncthreads();
  const int wq = t >> 6, cp = t & 63;
  for (int w0 = 0; w0 < 128; w0 += 4) {
    const int w = w0 + wq;
    const float v0 = tile[2 * cp][w], v1 = tile[2 * cp + 1][w];
    const size_t e = ((size_t)(b * 128 + w) * 128 + h) * 128 + 2 * cp;
    *(uint*)(xhi + e) = packhi(v0, v1);
    *(uint*)(xlo + e) = packtr(v0 - fhi(v0), v1 - fhi(v1));
  }
}

__global__ __launch_bounds__(256) void k_transpose_y(const float* __restrict__ y,
                                                     float* __restrict__ yt1,
                                                     float* __restrict__ yt2) {
  __shared__ float tile[128][129];
  const int b = blockIdx.x >> 7, h = blockIdx.x & 127;
  const int t = threadIdx.x, half = t >> 7, lane = t & 127;
  const float* src = y + (size_t)b * PLANE + (size_t)h * 128;
  for (int c0 = 0; c0 < 128; c0 += 2) {
    const int c = c0 + half;
    tile[c][lane] = src[(size_t)c * NPOS + lane];
  }
  __syncthreads();
  float* d1 = yt1 + (size_t)b * PLANE + (size_t)h * 128;
  float* d2 = yt2 + ((size_t)(b * 128 + h)) * NPOS;
  for (int w0 = 0; w0 < 128; w0 += 2) {
    const int w = w0 + half;
    const float v = tile[lane][w];
    d1[(size_t)w * NPOS + lane] = v;
    d2[(size_t)w * 128 + lane] = v;
  }
}

// ---------------------------------------------------------------------------
// 16-line batched gated scan, MFMA, bf16 3-term split, fragment-linear LDS.
// 4 waves; wave wv owns out rows [32wv,32wv+32) (tt=0,1 M-tiles).
// Lane l: line=l&15 (MFMA n), g4=l>>4 (k-group / C-row group).
// X/H planes [c][line]x16B: B-frag read at kt = plane + kt*1024 + l*16.
// Gate/old rings in per-wave C-layout slices: read = wv*2048 + tt*1024 + l*16.
// All fills: LDS dest = wave-uniform + lane*16; global src carries the layout.
// vmcnt: X/G/O all 3 steps deep; exact FIFO bounds 18/20/14 (ACCUM/OUT16/plain),
// used with margin 2 -> 16/18/12, placed BEFORE the barrier (cross-wave safety
// by induction through the barrier chain). Stores retire off-critical-path.
// ---------------------------------------------------------------------------
template <bool RELU0, bool REV, bool ACCUM, bool OUT16>
__device__ __forceinline__ void scan16(
    char* lds,
    const ushort* __restrict__ xhi, const ushort* __restrict__ xlo, size_t in_base,
    const float* __restrict__ gate, size_t gate_base,
    float* __restrict__ outf, ushort* __restrict__ outhi, ushort* __restrict__ outlo,
    size_t out_base, int out_ps, int out_ls,
    const float* __restrict__ Wa, const float* __restrict__ Ba,
    const float* __restrict__ Wb, const float* __restrict__ Bb) {
  const int t = threadIdx.x;
  const int wv = t >> 6, l = t & 63;
  const int line = l & 15, g4 = l >> 4;

  // resident weight fragments (A-layout: row=32wv+16tt+line, k=32kt+8g4+j)
  short8 wah[2][4], wal[2][4], wbh[2][4], wbl[2][4];
#pragma unroll
  for (int tt = 0; tt < 2; ++tt)
#pragma unroll
    for (int kt = 0; kt < 4; ++kt) {
      const int row = 32 * wv + 16 * tt + line;
      const int kc = 32 * kt + 8 * g4;
      split8(*(const float4*)(Wa + row * 128 + kc), *(const float4*)(Wa + row * 128 + kc + 4),
             wah[tt][kt], wal[tt][kt]);
      split8(*(const float4*)(Wb + row * 128 + kc), *(const float4*)(Wb + row * 128 + kc + 4),
             wbh[tt][kt], wbl[tt][kt]);
    }
  f32x4 baf[2], bbf[2];
#pragma unroll
  for (int tt = 0; tt < 2; ++tt) {
    baf[tt] = *(const f32x4*)(Ba + 32 * wv + 16 * tt + 4 * g4);
    bbf[tt] = *(const f32x4*)(Bb + 32 * wv + 16 * tt + 4 * g4);
  }

  auto P = [](int p) -> int { return REV ? 127 - p : p; };

  const int sp = wv >> 1;               // X split this wave fills
  const ushort* xsrc = sp ? xlo : xhi;
  const int lf = l & 15;                // line this lane fetches

  auto fillX = [&](int p, int slot) {
#pragma unroll
    for (int f = 0; f < 2; ++f) {
      const int kg = 2 * (wv & 1) + f;  // chunk group (4 chunks)
      const int cc = 4 * kg + (l >> 4);
      fill16(xsrc + in_base + (size_t)lf * NPOS + (size_t)p * 128 + 8 * cc,
             lds + XR_OFF + slot * 8192 + sp * 4096 + kg * 1024 + l * 16);
    }
  };
  auto fillG = [&](int p, int slot) {
#pragma unroll
    for (int f = 0; f < 2; ++f)
      fill16(gate + gate_base + (size_t)lf * NPOS + (size_t)p * 128 + 32 * wv + 16 * f + 4 * (l >> 4),
             lds + GR_OFF + slot * 8192 + wv * 2048 + f * 1024 + l * 16);
  };
  auto fillO = [&](int p, int slot) {
#pragma unroll
    for (int f = 0; f < 2; ++f)
      fill16(outf + out_base + (size_t)p * out_ps + (size_t)lf * out_ls + 32 * wv + 16 * f + 4 * (l >> 4),
             lds + OR_OFF + slot * 8192 + wv * 2048 + f * 1024 + l * 16);
  };

  // prologue: X slots 0..3, G slots 0..2 (gate first used step 1), O 0..3
#pragma unroll
  for (int p = 0; p < 4; ++p) {
    fillX(P(p), p);
    if (p < 3) fillG(P(p), p);
    if (ACCUM) fillO(P(p), p);
  }
  asm volatile("s_waitcnt vmcnt(0) lgkmcnt(0)\n\ts_barrier" ::: "memory");

  // ---- step 0: h0 = relu?(x[P(0)]) (C-layout read of X slot 0) ----
  {
    char* Hwr = lds + HP_OFF;
#pragma unroll
    for (int tt = 0; tt < 2; ++tt) {
      const int cw = 4 * wv + 2 * tt + (g4 >> 1);
      const int boff = (cw * 16 + line) * 16 + 8 * (g4 & 1);
      const uint2 xh = *(const uint2*)(lds + XR_OFF + boff);
      const uint2 xl = *(const uint2*)(lds + XR_OFF + 4096 + boff);
      float4 f;
      f.x = b2f(xh.x & 0xFFFFu) + b2f(xl.x & 0xFFFFu);
      f.y = b2f(xh.x >> 16) + b2f(xl.x >> 16);
      f.z = b2f(xh.y & 0xFFFFu) + b2f(xl.y & 0xFFFFu);
      f.w = b2f(xh.y >> 16) + b2f(xl.y >> 16);
      if (RELU0) {
        f.x = fmaxf(f.x, 0.f); f.y = fmaxf(f.y, 0.f);
        f.z = fmaxf(f.z, 0.f); f.w = fmaxf(f.w, 0.f);
      }
      uint2 hw, lw;
      hw.x = packhi(f.x, f.y); hw.y = packhi(f.z, f.w);
      lw.x = packtr(f.x - fhi(f.x), f.y - fhi(f.y));
      lw.y = packtr(f.z - fhi(f.z), f.w - fhi(f.w));
      *(uint2*)(Hwr + boff) = hw;
      *(uint2*)(Hwr + 4096 + boff) = lw;
      const int ci0 = 32 * wv + 16 * tt + 4 * g4;
      const size_t oe = out_base + (size_t)P(0) * out_ps + (size_t)line * out_ls + ci0;
      if (OUT16) {
        *(uint2*)(outhi + oe) = hw;
        *(uint2*)(outlo + oe) = lw;
      } else {
        float4 o = f;
        if (ACCUM) {
          const f32x4 ov = *(const f32x4*)(lds + OR_OFF + wv * 2048 + tt * 1024 + l * 16);
          o.x += ov[0]; o.y += ov[1]; o.z += ov[2]; o.w += ov[3];
        }
        *(float4*)(outf + oe) = o;
      }
    }
  }
  BAR();

  // ---- main loop ----
#pragma unroll 1
  for (int s = 1; s < 128; ++s) {
    if (s <= 124) {
      fillX(P(s + 3), (s + 3) & 3);
      fillG(P(s + 2), (s + 2) & 3);
      if (ACCUM) fillO(P(s + 3), (s + 3) & 3);
    }

    f32x4 aF0 = baf[0], aF1 = baf[1], aR0 = bbf[0], aR1 = bbf[1];
    const char* H = lds + HP_OFF + ((s - 1) & 1) * 8192;
    const char* X = lds + XR_OFF + (s & 3) * 8192;
    __builtin_amdgcn_s_setprio(1);
#pragma unroll
    for (int kt = 0; kt < 4; ++kt) {
      const short8 hh = *(const short8*)(H + kt * 1024 + l * 16);
      const short8 hl = *(const short8*)(H + 4096 + kt * 1024 + l * 16);
      const short8 xh = *(const short8*)(X + kt * 1024 + l * 16);
      const short8 xl = *(const short8*)(X + 4096 + kt * 1024 + l * 16);
      aR0 = MF(wbh[0][kt], hh, aR0);
      aR1 = MF(wbh[1][kt], hh, aR1);
      aF0 = MF(wah[0][kt], xh, aF0);
      aF1 = MF(wah[1][kt], xh, aF1);
      aR0 = MF(wbh[0][kt], hl, aR0);
      aR1 = MF(wbh[1][kt], hl, aR1);
      aF0 = MF(wah[0][kt], xl, aF0);
      aF1 = MF(wah[1][kt], xl, aF1);
      aR0 = MF(wbl[0][kt], hh, aR0);
      aR1 = MF(wbl[1][kt], hh, aR1);
      aF0 = MF(wal[0][kt], xh, aF0);
      aF1 = MF(wal[1][kt], xh, aF1);
    }
    __builtin_amdgcn_s_setprio(0);

    const char* Grd = lds + GR_OFF + ((s - 1) & 3) * 8192 + wv * 2048;
    const char* Ord = lds + OR_OFF + (s & 3) * 8192 + wv * 2048;
    char* Hwr = lds + HP_OFF + (s & 1) * 8192;
    const f32x4 aR[2] = {aR0, aR1}, aF[2] = {aF0, aF1};
#pragma unroll
    for (int tt = 0; tt < 2; ++tt) {
      const f32x4 g = *(const f32x4*)(Grd + tt * 1024 + l * 16);
      float4 h;
      h.x = fmaxf(fmaf(aR[tt][0], g[0], aF[tt][0]), 0.f);
      h.y = fmaxf(fmaf(aR[tt][1], g[1], aF[tt][1]), 0.f);
      h.z = fmaxf(fmaf(aR[tt][2], g[2], aF[tt][2]), 0.f);
      h.w = fmaxf(fmaf(aR[tt][3], g[3], aF[tt][3]), 0.f);
      uint2 hw, lw;
      hw.x = packhi(h.x, h.y); hw.y = packhi(h.z, h.w);
      lw.x = packtr(h.x - fhi(h.x), h.y - fhi(h.y));
      lw.y = packtr(h.z - fhi(h.z), h.w - fhi(h.w));
      const int cw = 4 * wv + 2 * tt + (g4 >> 1);
      const int boff = (cw * 16 + line) * 16 + 8 * (g4 & 1);
      *(uint2*)(Hwr + boff) = hw;
      *(uint2*)(Hwr + 4096 + boff) = lw;
      const int ci0 = 32 * wv + 16 * tt + 4 * g4;
      const size_t oe = out_base + (size_t)P(s) * out_ps + (size_t)line * out_ls + ci0;
      if (OUT16) {
        *(uint2*)(outhi + oe) = hw;
        *(uint2*)(outlo + oe) = lw;
      } else {
        float4 o = h;
        if (ACCUM) {
          const f32x4 ov = *(const f32x4*)(Ord + tt * 1024 + l * 16);
          o.x += ov[0]; o.y += ov[1]; o.z += ov[2]; o.w += ov[3];
        }
        *(float4*)(outf + oe) = o;
      }
    }
    // counted vmcnt BEFORE the barrier (exact bounds 18/20/14, margin 2)
    if constexpr (ACCUM)
      asm volatile("s_waitcnt vmcnt(16)" ::: "memory");
    else if constexpr (OUT16)
      asm volatile("s_waitcnt vmcnt(18)" ::: "memory");
    else
      asm volatile("s_waitcnt vmcnt(12)" ::: "memory");
    BAR();
  }
}

// Phase 1: 64 blocks = [scan(2)][b(4)][wgrp(8)]
__global__ __launch_bounds__(256, 1) void k_scan_ph1(
    const ushort* __restrict__ xhi, const ushort* __restrict__ xlo,
    const float* __restrict__ yt1,
    ushort* __restrict__ hs_hi, ushort* __restrict__ hs_lo,
    ushort* __restrict__ hn_hi, ushort* __restrict__ hn_lo,
    const float* w1, const float* b1, const float* w2, const float* b2,
    const float* w9, const float* b9, const float* w10, const float* b10) {
  __shared__ __align__(16) char lds[LDS_PH1];
  const int id = blockIdx.x;
  const int scan = id >> 5, b = (id >> 3) & 3, wg = id & 7;
  const size_t in_base = ((size_t)(b * 128 + wg * 16)) * NPOS;
  const size_t out_base = (size_t)b * PLANE + (size_t)(wg * 16) * 128;
  if (scan == 0)
    scan16<false, false, false, true>(lds, xhi, xlo, in_base, yt1, in_base,
                                      nullptr, hs_hi, hs_lo, out_base, NPOS, 128,
                                      w1, b1, w2, b2);
  else
    scan16<true, true, false, true>(lds, xhi, xlo, in_base, yt1, in_base,
                                    nullptr, hn_hi, hn_lo, out_base, NPOS, 128,
                                    w9, b9, w10, b10);
}

// Phase 2: 64 blocks = [grp(2)][b(4)][hgrp(8)]; grp0: SE then SW(acc) -> outA;
// grp1: NE then NW(acc) -> outB.
__global__ __launch_bounds__(256, 1) void k_scan_ph2(
    const ushort* __restrict__ hs_hi, const ushort* __restrict__ hs_lo,
    const ushort* __restrict__ hn_hi, const ushort* __restrict__ hn_lo,
    const float* __restrict__ yt2, float* __restrict__ outA, float* __restrict__ outB,
    const float* w4, const float* b4, const float* w5, const float* b5,
    const float* w7, const float* b7, const float* w8, const float* b8,
    const float* w12, const float* b12, const float* w13, const float* b13,
    const float* w15, const float* b15, const float* w16, const float* b16) {
  __shared__ __align__(16) char lds[LDS_PH2];
  const int id = blockIdx.x;
  const int grp = id >> 5, b = (id >> 3) & 3, hg = id & 7;
  const size_t base = ((size_t)(b * 128 + hg * 16)) * NPOS;
  const ushort* ihi = grp ? hn_hi : hs_hi;
  const ushort* ilo = grp ? hn_lo : hs_lo;
  float* o = grp ? outB : outA;
  const float* wa1 = grp ? w12 : w4; const float* ba1 = grp ? b12 : b4;
  const float* wb1 = grp ? w13 : w5; const float* bb1 = grp ? b13 : b5;
  const float* wa2 = grp ? w15 : w7; const float* ba2 = grp ? b15 : b7;
  const float* wb2 = grp ? w16 : w8; const float* bb2 = grp ? b16 : b8;
  // out element [line=h][pos=w][c]: pos stride 128, line stride NPOS
  scan16<true, false, false, false>(lds, ihi, ilo, base, yt2, base,
                                    o, nullptr, nullptr, base, 128, NPOS,
                                    wa1, ba1, wb1, bb1);
  asm volatile("s_waitcnt vmcnt(0) lgkmcnt(0)\n\ts_barrier" ::: "memory");
  scan16<true, true, true, false>(lds, ihi, ilo, base, yt2, base,
                                  o, nullptr, nullptr, base, 128, NPOS,
                                  wa2, ba2, wb2, bb2);
}

// out[b][c][h][w] = outA[b][h][w][c] + outB[b][h][w][c]
__global__ __launch_bounds__(256) void k_final(const float* __restrict__ outA,
                                               const float* __restrict__ outB,
                                               float* __restrict__ out) {
  __shared__ float tile[128][129];
  const int b = blockIdx.x >> 7, h = blockIdx.x & 127;
  const int t = threadIdx.x, half = t >> 7, lane = t & 127;
  const float* pa = outA + ((size_t)(b * 128 + h)) * NPOS;
  const float* pb = outB + ((size_t)(b * 128 + h)) * NPOS;
  for (int w0 = 0; w0 < 128; w0 += 2) {
    const int w = w0 + half;
    tile[w][lane] = pa[(size_t)w * 128 + lane] + pb[(size_t)w * 128 + lane];
  }
  __syncthreads();
  float* dst = out + (size_t)b * PLANE + (size_t)h * 128;
  for (int c0 = 0; c0 < 128; c0 += 2) {
    const int c = c0 + half;
    dst[(size_t)c * NPOS + lane] = tile[lane][c];
  }
}

extern "C" void kernel_launch(void* const* d_in, const int* in_sizes, int n_in,
                              void* d_out, int out_size, void* d_ws, size_t ws_size,
                              hipStream_t stream) {
  const float* x = (const float*)d_in[0];
  const float* y = (const float*)d_in[1];
  const float* w1 = (const float*)d_in[2];  const float* b1 = (const float*)d_in[3];
  const float* w2 = (const float*)d_in[4];  const float* b2 = (const float*)d_in[5];
  const float* w4 = (const float*)d_in[6];  const float* b4 = (const float*)d_in[7];
  const float* w5 = (const float*)d_in[8];  const float* b5 = (const float*)d_in[9];
  const float* w7 = (const float*)d_in[10]; const float* b7 = (const float*)d_in[11];
  const float* w8 = (const float*)d_in[12]; const float* b8 = (const float*)d_in[13];
  const float* w9 = (const float*)d_in[14]; const float* b9 = (const float*)d_in[15];
  const float* w10 = (const float*)d_in[16]; const float* b10 = (const float*)d_in[17];
  const float* w12 = (const float*)d_in[18]; const float* b12 = (const float*)d_in[19];
  const float* w13 = (const float*)d_in[20]; const float* b13 = (const float*)d_in[21];
  const float* w15 = (const float*)d_in[22]; const float* b15 = (const float*)d_in[23];
  const float* w16 = (const float*)d_in[24]; const float* b16 = (const float*)d_in[25];

  if (ws_size < 167772160) return;  // 160MB
  char* ws = (char*)d_ws;
  ushort* xt_hi = (ushort*)ws;                // 0   .. 16MB
  ushort* xt_lo = (ushort*)(ws + 16777216);   // 16  .. 32MB
  float* yt1 = (float*)(ws + 33554432);       // 32  .. 64MB
  float* yt2 = (float*)(ws + 67108864);       // 64  .. 96MB
  ushort* hs_hi = (ushort*)(ws + 100663296);  // 96  .. 112MB
  ushort* hs_lo = (ushort*)(ws + 117440512);  // 112 .. 128MB
  ushort* hn_hi = (ushort*)(ws + 134217728);  // 128 .. 144MB
  ushort* hn_lo = (ushort*)(ws + 150994944);  // 144 .. 160MB
  float* outA = (float*)ws;                   // overlay xt (dead after ph1)
  float* outB = (float*)(ws + 33554432);      // overlay yt1 (dead after ph1)

  dim3 blk(256);
  k_transpose_x<<<512, blk, 0, stream>>>(x, xt_hi, xt_lo);
  k_transpose_y<<<512, blk, 0, stream>>>(y, yt1, yt2);
  k_scan_ph1<<<64, blk, 0, stream>>>(xt_hi, xt_lo, yt1, hs_hi, hs_lo, hn_hi, hn_lo,
                                     w1, b1, w2, b2, w9, b9, w10, b10);
  k_scan_ph2<<<64, blk, 0, stream>>>(hs_hi, hs_lo, hn_hi, hn_lo, yt2, outA, outB,
                                     w4, b4, w5, b5, w7, b7, w8, b8,
                                     w12, b12, w13, b13, w15, b15, w16, b16);
  k_final<<<512, blk, 0, stream>>>(outA, outB, (float*)d_out);
}